// Round 2
// baseline (1024.215 us; speedup 1.0000x reference)
//
#include <hip/hip_runtime.h>

// NystromAttention on MI355X. fp32 inputs/outputs (per reference setup_inputs),
// fp32 internal math. Intermediates in d_ws (~25.2 MB).

typedef unsigned int uint_t;

#define NB 4
#define NH 12
#define BH 48
#define SQ 4096
#define HD 64
#define NL 128
#define SEG 32
#define SCALE 0.35355339059327379f
#define NEGBIG 1.0e9f

// ---------------- 1. landmark means (Q_lm, K_lm), scale+mask folded ----------------
__global__ void lm_kernel(const float* __restrict__ Q, const float* __restrict__ K,
                          const float* __restrict__ M,
                          float* __restrict__ Qlm, float* __restrict__ Klm,
                          uint_t* __restrict__ scal) {
    int bhl = blockIdx.x;            // bh*128 + l
    int bh  = bhl >> 7;
    int l   = bhl & 127;
    int b   = bh / NH;
    const float* src = blockIdx.y ? K : Q;
    float* dst = blockIdx.y ? Klm : Qlm;
    int d = threadIdx.x;             // 64 threads
    size_t base = ((size_t)bh * SQ + (size_t)l * SEG) * HD + d;
    int mbase = b * SQ + l * SEG;
    float acc = 0.f;
#pragma unroll 8
    for (int j = 0; j < SEG; ++j)
        acc += src[base + (size_t)j * HD] * M[mbase + j];
    dst[(size_t)bhl * HD + d] = acc * (SCALE / (float)SEG);
    if (bhl == 0 && blockIdx.y == 0 && d < 2) scal[d] = 0u;
}

// ---------------- 2. kernel_2 = softmax(Qlm @ Klm^T), plus row sums ----------------
__global__ void k2_kernel(const float* __restrict__ Qlm, const float* __restrict__ Klm,
                          float* __restrict__ K2, float* __restrict__ rowsum) {
    int bh = blockIdx.x >> 7;
    int c  = threadIdx.x;            // 128 threads = one column each
    __shared__ float q[HD];
    __shared__ float red[NL];
    if (c < HD) q[c] = Qlm[(size_t)blockIdx.x * HD + c];
    __syncthreads();
    const float* krow = Klm + ((size_t)bh * NL + c) * HD;
    float s = 0.f;
#pragma unroll 16
    for (int d = 0; d < HD; ++d) s += q[d] * krow[d];
    red[c] = s; __syncthreads();
    for (int st = 64; st > 0; st >>= 1) { if (c < st) red[c] = fmaxf(red[c], red[c + st]); __syncthreads(); }
    float mx = red[0]; __syncthreads();
    float e = __expf(s - mx);
    red[c] = e; __syncthreads();
    for (int st = 64; st > 0; st >>= 1) { if (c < st) red[c] += red[c + st]; __syncthreads(); }
    float inv = 1.f / red[0]; __syncthreads();
    float p = e * inv;
    K2[(size_t)blockIdx.x * NL + c] = p;
    red[c] = p; __syncthreads();
    for (int st = 64; st > 0; st >>= 1) { if (c < st) red[c] += red[c + st]; __syncthreads(); }
    if (c == 0) rowsum[blockIdx.x] = red[0];
}

// ---------------- 3. global max col-sum / row-sum -> init_scale ingredients ----------------
__global__ void colmax_kernel(const float* __restrict__ K2, const float* __restrict__ rowsum,
                              uint_t* __restrict__ scal) {
    int bh = blockIdx.x;
    int c  = threadIdx.x;            // 128
    __shared__ float red[NL];
    float cs = 0.f;
    for (int r = 0; r < NL; ++r) cs += K2[((size_t)bh * NL + r) * NL + c];
    red[c] = cs; __syncthreads();
    for (int st = 64; st > 0; st >>= 1) { if (c < st) red[c] = fmaxf(red[c], red[c + st]); __syncthreads(); }
    if (c == 0) atomicMax(&scal[0], __float_as_uint(red[0]));
    __syncthreads();
    float rs = rowsum[bh * NL + c];
    red[c] = rs; __syncthreads();
    for (int st = 64; st > 0; st >>= 1) { if (c < st) red[c] = fmaxf(red[c], red[c + st]); __syncthreads(); }
    if (c == 0) atomicMax(&scal[1], __float_as_uint(red[0]));
}

// ---------------- 4. Vm0 = init_scale * K2^T ----------------
__global__ void initv_kernel(const float* __restrict__ K2, const uint_t* __restrict__ scal,
                             float* __restrict__ V0) {
    float sc = 1.f / (__uint_as_float(scal[0]) * __uint_as_float(scal[1]));
    int bh = blockIdx.x >> 7, i = blockIdx.x & 127, j = threadIdx.x;
    V0[(size_t)blockIdx.x * NL + j] = sc * K2[((size_t)bh * NL + j) * NL + i];
}

// ---------------- 5. batched 128x128x128 matmul: C = alpha * A @ (beta*I - B | B) ----------------
__global__ __launch_bounds__(256) void nw_matmul(const float* __restrict__ A, const float* __restrict__ B,
                                                 float* __restrict__ C, float alpha, float beta, int mode) {
    int bh = blockIdx.y;
    int r0 = blockIdx.x * 32;
    const float* Ab = A + (size_t)bh * NL * NL;
    const float* Bb = B + (size_t)bh * NL * NL;
    float* Cb = C + (size_t)bh * NL * NL;
    __shared__ float As[32][33];
    __shared__ float Bs[32][128];
    int tid = threadIdx.x;
    int tx = tid & 31, ty = tid >> 5;   // ty 0..7
    float acc[4][4] = {};
    for (int kt = 0; kt < NL; kt += 32) {
        { int k = tid & 31, r4 = tid >> 5;
#pragma unroll
          for (int i = 0; i < 4; ++i) { int r = r4 * 4 + i; As[r][k] = Ab[(size_t)(r0 + r) * NL + kt + k]; } }
#pragma unroll
        for (int rep = 0; rep < 4; ++rep) {
            int idx = rep * 256 + tid;          // 1024 float4s
            int krow = idx >> 5;
            int c4 = (idx & 31) * 4;
            float4 v = *(const float4*)(Bb + (size_t)(kt + krow) * NL + c4);
            if (mode) {
                int kg = kt + krow;
                v.x = (kg == c4 + 0 ? beta : 0.f) - v.x;
                v.y = (kg == c4 + 1 ? beta : 0.f) - v.y;
                v.z = (kg == c4 + 2 ? beta : 0.f) - v.z;
                v.w = (kg == c4 + 3 ? beta : 0.f) - v.w;
            }
            *(float4*)&Bs[krow][c4] = v;
        }
        __syncthreads();
#pragma unroll 8
        for (int k = 0; k < 32; ++k) {
            float a[4], bb[4];
#pragma unroll
            for (int i = 0; i < 4; ++i) a[i] = As[ty * 4 + i][k];
#pragma unroll
            for (int j = 0; j < 4; ++j) bb[j] = Bs[k][tx + 32 * j];
#pragma unroll
            for (int i = 0; i < 4; ++i)
#pragma unroll
                for (int j = 0; j < 4; ++j) acc[i][j] += a[i] * bb[j];
        }
        __syncthreads();
    }
#pragma unroll
    for (int i = 0; i < 4; ++i)
#pragma unroll
        for (int j = 0; j < 4; ++j)
            Cb[(size_t)(r0 + ty * 4 + i) * NL + tx + 32 * j] = alpha * acc[i][j];
}

// ---------------- 6. A = softmax(Qlm @ Ks^T - big*(1-mask)) @ V  (online softmax) ----------------
__global__ __launch_bounds__(256) void k3v_kernel(const float* __restrict__ K, const float* __restrict__ V,
                                                  const float* __restrict__ M, const float* __restrict__ Qlm,
                                                  float* __restrict__ A) {
    int bh = blockIdx.y, b = bh / NH;
    int l0 = blockIdx.x * 16;
    __shared__ float ql[16][64];
    __shared__ float Ksh[64][65];
    __shared__ float Vsh[64][65];
    __shared__ float mk[64];
    __shared__ float sc[16][65];
    __shared__ float oacc[16][64];
    __shared__ float mrow[16], lrow[16], arow[16];
    __shared__ float red[16][16];
    int tid = threadIdx.x;
    for (int idx = tid; idx < 1024; idx += 256) {
        int r = idx >> 6, d = idx & 63;
        ql[r][d] = Qlm[((size_t)bh * NL + l0 + r) * HD + d];
        oacc[r][d] = 0.f;
    }
    if (tid < 16) { mrow[tid] = -1e30f; lrow[tid] = 0.f; }
    __syncthreads();
    const float4* Kg = (const float4*)(K + (size_t)bh * SQ * HD);
    const float4* Vg = (const float4*)(V + (size_t)bh * SQ * HD);
    for (int kt = 0; kt < SQ; kt += 64) {
        int base4 = kt * 16;               // float4 index of tile start
#pragma unroll
        for (int rep = 0; rep < 4; ++rep) {
            int v = rep * 256 + tid;       // 0..1023 = 64 rows x 16 float4
            int row = v >> 4, c4 = (v & 15) * 4;
            float4 x = Kg[base4 + v];
            Ksh[row][c4] = x.x; Ksh[row][c4 + 1] = x.y; Ksh[row][c4 + 2] = x.z; Ksh[row][c4 + 3] = x.w;
            float4 y = Vg[base4 + v];
            Vsh[row][c4] = y.x; Vsh[row][c4 + 1] = y.y; Vsh[row][c4 + 2] = y.z; Vsh[row][c4 + 3] = y.w;
        }
        if (tid < 64) mk[tid] = M[b * SQ + kt + tid];
        __syncthreads();
        // scores: thread -> key k (0..63), 4 rows each
        int k = tid & 63, rg = tid >> 6;   // rg 0..3
        float a4[4] = {};
#pragma unroll 16
        for (int d = 0; d < 64; ++d) {
            float kv = Ksh[k][d];
#pragma unroll
            for (int i = 0; i < 4; ++i) a4[i] += ql[rg * 4 + i][d] * kv;
        }
        {
            float mval = mk[k];
            float bias = -NEGBIG * (1.f - mval);
            float ms = mval * SCALE;
#pragma unroll
            for (int i = 0; i < 4; ++i) sc[rg * 4 + i][k] = a4[i] * ms + bias;
        }
        __syncthreads();
        // online softmax bookkeeping
        int r = tid >> 4, sg = tid & 15;
        float mx = fmaxf(fmaxf(sc[r][sg * 4], sc[r][sg * 4 + 1]), fmaxf(sc[r][sg * 4 + 2], sc[r][sg * 4 + 3]));
        red[r][sg] = mx;
        __syncthreads();
        if (tid < 16) {
            float m2 = red[tid][0];
#pragma unroll
            for (int j = 1; j < 16; ++j) m2 = fmaxf(m2, red[tid][j]);
            float Mn = fmaxf(mrow[tid], m2);
            arow[tid] = __expf(mrow[tid] - Mn);
            mrow[tid] = Mn;
        }
        __syncthreads();
        float Mn = mrow[r];
        float psum = 0.f;
#pragma unroll
        for (int j = 0; j < 4; ++j) {
            float e = __expf(sc[r][sg * 4 + j] - Mn);
            sc[r][sg * 4 + j] = e;
            psum += e;
        }
        red[r][sg] = psum;
        __syncthreads();
        if (tid < 16) {
            float ssum = 0.f;
#pragma unroll
            for (int j = 0; j < 16; ++j) ssum += red[tid][j];
            lrow[tid] = lrow[tid] * arow[tid] + ssum;
        }
        // PV accumulate: d = tid&63, rows vg*4..+3
        int d = tid & 63, vg = tid >> 6;
        float t4[4] = {};
        for (int kk = 0; kk < 64; ++kk) {
            float vv = Vsh[kk][d];
#pragma unroll
            for (int i = 0; i < 4; ++i) t4[i] += sc[vg * 4 + i][kk] * vv;
        }
#pragma unroll
        for (int i = 0; i < 4; ++i) {
            int rr = vg * 4 + i;
            oacc[rr][d] = oacc[rr][d] * arow[rr] + t4[i];
        }
        __syncthreads();
    }
    for (int idx = tid; idx < 1024; idx += 256) {
        int r = idx >> 6, d = idx & 63;
        A[((size_t)bh * NL + l0 + r) * HD + d] = oacc[r][d] / lrow[r];
    }
}

// ---------------- 7. W = Vinv @ A ----------------
__global__ __launch_bounds__(256) void w_kernel(const float* __restrict__ Vinv, const float* __restrict__ A,
                                                float* __restrict__ W) {
    int bh = blockIdx.y;
    int r0 = blockIdx.x * 32;
    __shared__ float Ash[128][64];
    __shared__ float Vl[32][129];
    int tid = threadIdx.x;
    for (int idx = tid; idx < 8192; idx += 256) Ash[idx >> 6][idx & 63] = A[(size_t)bh * 8192 + idx];
    for (int idx = tid; idx < 4096; idx += 256) {
        int r = idx >> 7, k = idx & 127;
        Vl[r][k] = Vinv[(size_t)bh * 16384 + (size_t)(r0 + r) * NL + k];
    }
    __syncthreads();
    int d = tid & 63, rg = tid >> 6;
    float acc[8] = {};
    for (int k = 0; k < NL; ++k) {
        float av = Ash[k][d];
#pragma unroll
        for (int i = 0; i < 8; ++i) acc[i] += Vl[rg * 8 + i][k] * av;
    }
#pragma unroll
    for (int i = 0; i < 8; ++i)
        W[(size_t)bh * 8192 + (size_t)(r0 + rg * 8 + i) * HD + d] = acc[i];
}

// ---------------- 8. X = softmax(Qs @ Klm^T) @ W  -> fp32 out ----------------
__global__ __launch_bounds__(256) void k1x_kernel(const float* __restrict__ Q, const float* __restrict__ M,
                                                  const float* __restrict__ Klm, const float* __restrict__ W,
                                                  float* __restrict__ out) {
    int bh = blockIdx.y, b = bh / NH;
    int q0 = blockIdx.x * 64;
    __shared__ float Ql[64][64];
    __shared__ float P[64][133];
    __shared__ float Kc[128][17];
    __shared__ float rmax[64], rinv[64];
    __shared__ float red[64][4];
    int tid = threadIdx.x;
    const float4* Qg = (const float4*)(Q + (size_t)(bh * SQ + q0) * HD);
#pragma unroll
    for (int rep = 0; rep < 4; ++rep) {
        int idx = rep * 256 + tid;         // 1024 float4 = 64 rows x 16
        int r = idx >> 4, c4 = (idx & 15) * 4;
        float4 u = Qg[idx];
        float mm = M[b * SQ + q0 + r] * SCALE;
        Ql[r][c4]     = u.x * mm;
        Ql[r][c4 + 1] = u.y * mm;
        Ql[r][c4 + 2] = u.z * mm;
        Ql[r][c4 + 3] = u.w * mm;
    }
    int lg = tid & 31, rg = tid >> 5;      // l = lg*4+j , rows rg*8+i
    float acc[8][4] = {};
    for (int dc = 0; dc < 4; ++dc) {
        __syncthreads();
        for (int idx = tid; idx < 2048; idx += 256) {
            int l = idx >> 4, m = idx & 15;
            Kc[l][m] = Klm[((size_t)bh * NL + l) * HD + dc * 16 + m];
        }
        __syncthreads();
#pragma unroll 4
        for (int m = 0; m < 16; ++m) {
            float kv[4];
#pragma unroll
            for (int j = 0; j < 4; ++j) kv[j] = Kc[lg * 4 + j][m];
#pragma unroll
            for (int i = 0; i < 8; ++i) {
                float qv = Ql[rg * 8 + i][dc * 16 + m];
#pragma unroll
                for (int j = 0; j < 4; ++j) acc[i][j] += qv * kv[j];
            }
        }
    }
#pragma unroll
    for (int i = 0; i < 8; ++i)
#pragma unroll
        for (int j = 0; j < 4; ++j) P[rg * 8 + i][lg * 4 + j] = acc[i][j];
    __syncthreads();
    // softmax over 128 landmarks per row
    int r = tid & 63, sg = tid >> 6;       // sg 0..3 scans 32 each
    float mx = -1e30f;
#pragma unroll 8
    for (int j = 0; j < 32; ++j) mx = fmaxf(mx, P[r][sg * 32 + j]);
    red[r][sg] = mx;
    __syncthreads();
    if (sg == 0) rmax[r] = fmaxf(fmaxf(red[r][0], red[r][1]), fmaxf(red[r][2], red[r][3]));
    __syncthreads();
    float M2 = rmax[r];
    float ps = 0.f;
#pragma unroll 8
    for (int j = 0; j < 32; ++j) {
        float e = __expf(P[r][sg * 32 + j] - M2);
        P[r][sg * 32 + j] = e;
        ps += e;
    }
    red[r][sg] = ps;
    __syncthreads();
    if (sg == 0) rinv[r] = 1.f / (red[r][0] + red[r][1] + red[r][2] + red[r][3]);
    __syncthreads();
    // PV: X = P @ W (fold 1/sum at store)
    int d2 = tid & 31, rg8 = tid >> 5;
    const float2* Wg = (const float2*)(W + (size_t)bh * 8192);
    float a2[8][2] = {};
    for (int l = 0; l < NL; ++l) {
        float2 w = Wg[l * 32 + d2];
#pragma unroll
        for (int i = 0; i < 8; ++i) {
            float p = P[rg8 * 8 + i][l];
            a2[i][0] += p * w.x;
            a2[i][1] += p * w.y;
        }
    }
    float* outp = out + (size_t)(bh * SQ + q0) * HD;
#pragma unroll
    for (int i = 0; i < 8; ++i) {
        int r2 = rg8 * 8 + i;
        float s = rinv[r2];
        float2 o = make_float2(a2[i][0] * s, a2[i][1] * s);
        *(float2*)&outp[r2 * HD + 2 * d2] = o;
    }
}

extern "C" void kernel_launch(void* const* d_in, const int* in_sizes, int n_in,
                              void* d_out, int out_size, void* d_ws, size_t ws_size,
                              hipStream_t stream) {
    const float* Q = (const float*)d_in[0];
    const float* K = (const float*)d_in[1];
    const float* V = (const float*)d_in[2];
    const float* M = (const float*)d_in[3];
    float* out = (float*)d_out;

    float* ws  = (float*)d_ws;
    float* Qlm = ws;                 // 48*128*64
    float* Klm = Qlm + 393216;
    float* K2  = Klm + 393216;       // 48*128*128
    float* Vm0 = K2  + 786432;
    float* Vm1 = Vm0 + 786432;
    float* KV  = Vm1 + 786432;
    float* T1  = KV  + 786432;
    float* T2  = T1  + 786432;
    float* Ab  = T2  + 786432;       // 48*128*64
    float* Wb  = Ab  + 393216;
    float* rowsum = Wb + 393216;     // 6144
    uint_t* scal  = (uint_t*)(rowsum + 6144);

    lm_kernel<<<dim3(6144, 2), 64, 0, stream>>>(Q, K, M, Qlm, Klm, scal);
    k2_kernel<<<6144, 128, 0, stream>>>(Qlm, Klm, K2, rowsum);
    colmax_kernel<<<48, 128, 0, stream>>>(K2, rowsum, scal);
    initv_kernel<<<6144, 128, 0, stream>>>(K2, scal, Vm0);

    float* Vc = Vm0; float* Vn = Vm1;
    for (int it = 0; it < 6; ++it) {
        nw_matmul<<<dim3(4, 48), 256, 0, stream>>>(K2, Vc, KV, 1.f, 0.f, 0);   // KV = Km@Vm
        nw_matmul<<<dim3(4, 48), 256, 0, stream>>>(KV, KV, T1, 1.f, 7.f, 1);   // T1 = KV@(7I-KV)
        nw_matmul<<<dim3(4, 48), 256, 0, stream>>>(KV, T1, T2, 1.f, 15.f, 1);  // T2 = KV@(15I-T1)
        nw_matmul<<<dim3(4, 48), 256, 0, stream>>>(Vc, T2, Vn, 0.25f, 13.f, 1);// Vn = .25*Vm@(13I-T2)
        float* t = Vc; Vc = Vn; Vn = t;
    }

    k3v_kernel<<<dim3(8, 48), 256, 0, stream>>>(K, V, M, Qlm, Ab);
    w_kernel<<<dim3(4, 48), 256, 0, stream>>>(Vc, Ab, Wb);
    k1x_kernel<<<dim3(64, 48), 256, 0, stream>>>(Q, M, Klm, Wb, out);
}

// Round 3
// 590.024 us; speedup vs baseline: 1.7359x; 1.7359x over previous
//
#include <hip/hip_runtime.h>

// NystromAttention on MI355X. fp32 I/O, bf16 MFMA for the two big attention
// matmuls (k3v flash + k1x), fp32 elsewhere. Newton chain still fp32 vector.

typedef unsigned int uint_t;
typedef unsigned short ushort_t;
typedef short s16x8 __attribute__((ext_vector_type(8)));
typedef float f32x4 __attribute__((ext_vector_type(4)));

#define NB 4
#define NH 12
#define BH 48
#define SQ 4096
#define HD 64
#define NL 128
#define SEG 32
#define SCALE 0.35355339059327379f
#define NEGBIG 1.0e9f

__device__ __forceinline__ ushort_t f2bf(float f) {
    uint_t u = __float_as_uint(f);
    u += 0x7FFFu + ((u >> 16) & 1u);   // RNE
    return (ushort_t)(u >> 16);
}
__device__ __forceinline__ uint_t pack2(float a, float b) {
    return (uint_t)f2bf(a) | ((uint_t)f2bf(b) << 16);
}
__device__ __forceinline__ s16x8 ld_frag(const ushort_t* p) {
    return __builtin_bit_cast(s16x8, *(const uint4*)p);
}
#define MFMA16(a, b, c) __builtin_amdgcn_mfma_f32_16x16x32_bf16(a, b, c, 0, 0, 0)

// ---------------- 1. landmark means (Q_lm, K_lm), scale+mask folded ----------------
__global__ void lm_kernel(const float* __restrict__ Q, const float* __restrict__ K,
                          const float* __restrict__ M,
                          float* __restrict__ Qlm, float* __restrict__ Klm,
                          uint_t* __restrict__ scal) {
    int bhl = blockIdx.x;            // bh*128 + l
    int bh  = bhl >> 7;
    int l   = bhl & 127;
    int b   = bh / NH;
    const float* src = blockIdx.y ? K : Q;
    float* dst = blockIdx.y ? Klm : Qlm;
    int d = threadIdx.x;             // 64 threads
    size_t base = ((size_t)bh * SQ + (size_t)l * SEG) * HD + d;
    int mbase = b * SQ + l * SEG;
    float acc = 0.f;
#pragma unroll 8
    for (int j = 0; j < SEG; ++j)
        acc += src[base + (size_t)j * HD] * M[mbase + j];
    dst[(size_t)bhl * HD + d] = acc * (SCALE / (float)SEG);
    if (bhl == 0 && blockIdx.y == 0 && d < 2) scal[d] = 0u;
}

// ---------------- 2. kernel_2 = softmax(Qlm @ Klm^T), plus row sums ----------------
__global__ void k2_kernel(const float* __restrict__ Qlm, const float* __restrict__ Klm,
                          float* __restrict__ K2, float* __restrict__ rowsum) {
    int bh = blockIdx.x >> 7;
    int c  = threadIdx.x;            // 128 threads = one column each
    __shared__ float q[HD];
    __shared__ float red[NL];
    if (c < HD) q[c] = Qlm[(size_t)blockIdx.x * HD + c];
    __syncthreads();
    const float* krow = Klm + ((size_t)bh * NL + c) * HD;
    float s = 0.f;
#pragma unroll 16
    for (int d = 0; d < HD; ++d) s += q[d] * krow[d];
    red[c] = s; __syncthreads();
    for (int st = 64; st > 0; st >>= 1) { if (c < st) red[c] = fmaxf(red[c], red[c + st]); __syncthreads(); }
    float mx = red[0]; __syncthreads();
    float e = __expf(s - mx);
    red[c] = e; __syncthreads();
    for (int st = 64; st > 0; st >>= 1) { if (c < st) red[c] += red[c + st]; __syncthreads(); }
    float inv = 1.f / red[0]; __syncthreads();
    float p = e * inv;
    K2[(size_t)blockIdx.x * NL + c] = p;
    red[c] = p; __syncthreads();
    for (int st = 64; st > 0; st >>= 1) { if (c < st) red[c] += red[c + st]; __syncthreads(); }
    if (c == 0) rowsum[blockIdx.x] = red[0];
}

// ---------------- 3. global max col-sum / row-sum -> init_scale ingredients ----------------
__global__ void colmax_kernel(const float* __restrict__ K2, const float* __restrict__ rowsum,
                              uint_t* __restrict__ scal) {
    int bh = blockIdx.x;
    int c  = threadIdx.x;            // 128
    __shared__ float red[NL];
    float cs = 0.f;
    for (int r = 0; r < NL; ++r) cs += K2[((size_t)bh * NL + r) * NL + c];
    red[c] = cs; __syncthreads();
    for (int st = 64; st > 0; st >>= 1) { if (c < st) red[c] = fmaxf(red[c], red[c + st]); __syncthreads(); }
    if (c == 0) atomicMax(&scal[0], __float_as_uint(red[0]));
    __syncthreads();
    float rs = rowsum[bh * NL + c];
    red[c] = rs; __syncthreads();
    for (int st = 64; st > 0; st >>= 1) { if (c < st) red[c] = fmaxf(red[c], red[c + st]); __syncthreads(); }
    if (c == 0) atomicMax(&scal[1], __float_as_uint(red[0]));
}

// ---------------- 4. Vm0 = init_scale * K2^T ----------------
__global__ void initv_kernel(const float* __restrict__ K2, const uint_t* __restrict__ scal,
                             float* __restrict__ V0) {
    float sc = 1.f / (__uint_as_float(scal[0]) * __uint_as_float(scal[1]));
    int bh = blockIdx.x >> 7, i = blockIdx.x & 127, j = threadIdx.x;
    V0[(size_t)blockIdx.x * NL + j] = sc * K2[((size_t)bh * NL + j) * NL + i];
}

// ---------------- 5. batched 128x128x128 matmul: C = alpha * A @ (beta*I - B | B) ----------------
__global__ __launch_bounds__(256) void nw_matmul(const float* __restrict__ A, const float* __restrict__ B,
                                                 float* __restrict__ C, float alpha, float beta, int mode) {
    int bh = blockIdx.y;
    int r0 = blockIdx.x * 32;
    const float* Ab = A + (size_t)bh * NL * NL;
    const float* Bb = B + (size_t)bh * NL * NL;
    float* Cb = C + (size_t)bh * NL * NL;
    __shared__ float As[32][33];
    __shared__ float Bs[32][128];
    int tid = threadIdx.x;
    int tx = tid & 31, ty = tid >> 5;   // ty 0..7
    float acc[4][4] = {};
    for (int kt = 0; kt < NL; kt += 32) {
        { int k = tid & 31, r4 = tid >> 5;
#pragma unroll
          for (int i = 0; i < 4; ++i) { int r = r4 * 4 + i; As[r][k] = Ab[(size_t)(r0 + r) * NL + kt + k]; } }
#pragma unroll
        for (int rep = 0; rep < 4; ++rep) {
            int idx = rep * 256 + tid;          // 1024 float4s
            int krow = idx >> 5;
            int c4 = (idx & 31) * 4;
            float4 v = *(const float4*)(Bb + (size_t)(kt + krow) * NL + c4);
            if (mode) {
                int kg = kt + krow;
                v.x = (kg == c4 + 0 ? beta : 0.f) - v.x;
                v.y = (kg == c4 + 1 ? beta : 0.f) - v.y;
                v.z = (kg == c4 + 2 ? beta : 0.f) - v.z;
                v.w = (kg == c4 + 3 ? beta : 0.f) - v.w;
            }
            *(float4*)&Bs[krow][c4] = v;
        }
        __syncthreads();
#pragma unroll 8
        for (int k = 0; k < 32; ++k) {
            float a[4], bb[4];
#pragma unroll
            for (int i = 0; i < 4; ++i) a[i] = As[ty * 4 + i][k];
#pragma unroll
            for (int j = 0; j < 4; ++j) bb[j] = Bs[k][tx + 32 * j];
#pragma unroll
            for (int i = 0; i < 4; ++i)
#pragma unroll
                for (int j = 0; j < 4; ++j) acc[i][j] += a[i] * bb[j];
        }
        __syncthreads();
    }
#pragma unroll
    for (int i = 0; i < 4; ++i)
#pragma unroll
        for (int j = 0; j < 4; ++j)
            Cb[(size_t)(r0 + ty * 4 + i) * NL + tx + 32 * j] = alpha * acc[i][j];
}

// ---------------- 6a. k3v flash, bf16 MFMA, key-split partials ----------------
// grid (8,48): block = (key-chunk of 512, bh). 4 waves x 32 landmark rows.
#define KT 64
#define KP 72            // padded LDS row stride in ushorts (144 B, 16B-aligned)
__global__ __launch_bounds__(256) void k3v_mfma(const float* __restrict__ K, const float* __restrict__ V,
                                                const float* __restrict__ M, const float* __restrict__ Qlm,
                                                float* __restrict__ Opart, float* __restrict__ Mpart,
                                                float* __restrict__ Lpart) {
    int bh = blockIdx.y, b = bh / NH, ck = blockIdx.x;
    int tid = threadIdx.x;
    int wave = tid >> 6, lane = tid & 63, quad = lane >> 4, l16 = lane & 15;
    __shared__ ushort_t Ksh[KT * KP];          // [key][d] bf16
    __shared__ ushort_t Vsh[HD * KP];          // [d][key] bf16 (transposed)
    __shared__ ushort_t Psh[4 * 32 * KP];      // per-wave P regions [row][key]
    __shared__ float msc[KT], mbias[KT];
    int R0 = wave * 32;
    // preload Q A-fragments (constant across key tiles)
    s16x8 aq[2][2];
#pragma unroll
    for (int rt = 0; rt < 2; ++rt)
#pragma unroll
        for (int ks = 0; ks < 2; ++ks) {
            const float* qp = Qlm + ((size_t)bh * NL + R0 + rt * 16 + l16) * HD + ks * 32 + quad * 8;
            float4 q0 = *(const float4*)qp;
            float4 q1 = *(const float4*)(qp + 4);
            aq[rt][ks] = __builtin_bit_cast(s16x8,
                make_uint4(pack2(q0.x, q0.y), pack2(q0.z, q0.w), pack2(q1.x, q1.y), pack2(q1.z, q1.w)));
        }
    float m_run[2][4], l_run[2][4];
    f32x4 o[2][4];
#pragma unroll
    for (int rt = 0; rt < 2; ++rt)
#pragma unroll
        for (int r = 0; r < 4; ++r) { m_run[rt][r] = -1e30f; l_run[rt][r] = 0.f; }
#pragma unroll
    for (int rt = 0; rt < 2; ++rt)
#pragma unroll
        for (int dn = 0; dn < 4; ++dn) o[rt][dn] = (f32x4){0.f, 0.f, 0.f, 0.f};

    const float4* Kg = (const float4*)(K + ((size_t)bh * SQ + ck * 512) * HD);
    const float4* Vg = (const float4*)(V + ((size_t)bh * SQ + ck * 512) * HD);
    const float* Mg = M + b * SQ + ck * 512;

    for (int t = 0; t < 8; ++t) {
        __syncthreads();
#pragma unroll
        for (int rep = 0; rep < 4; ++rep) {
            int idx = rep * 256 + tid;          // 1024 float4 = 64 keys x 16
            int key = idx >> 4, d4 = (idx & 15) * 4;
            float4 x = Kg[t * 1024 + idx];
            *(uint2*)&Ksh[key * KP + d4] = make_uint2(pack2(x.x, x.y), pack2(x.z, x.w));
            float4 y = Vg[t * 1024 + idx];
            Vsh[(d4 + 0) * KP + key] = f2bf(y.x);
            Vsh[(d4 + 1) * KP + key] = f2bf(y.y);
            Vsh[(d4 + 2) * KP + key] = f2bf(y.z);
            Vsh[(d4 + 3) * KP + key] = f2bf(y.w);
        }
        if (tid < KT) {
            float mv = Mg[t * KT + tid];
            msc[tid] = mv * SCALE;
            mbias[tid] = -NEGBIG * (1.f - mv);
        }
        __syncthreads();
#pragma unroll
        for (int rt = 0; rt < 2; ++rt) {
            f32x4 acc[4];
#pragma unroll
            for (int nt = 0; nt < 4; ++nt) acc[nt] = (f32x4){0.f, 0.f, 0.f, 0.f};
#pragma unroll
            for (int nt = 0; nt < 4; ++nt)
#pragma unroll
                for (int ks = 0; ks < 2; ++ks) {
                    s16x8 bf = ld_frag(&Ksh[(nt * 16 + l16) * KP + ks * 32 + quad * 8]);
                    acc[nt] = MFMA16(aq[rt][ks], bf, acc[nt]);
                }
            float s[4][4];
#pragma unroll
            for (int nt = 0; nt < 4; ++nt) {
                float mm = msc[nt * 16 + l16], bb = mbias[nt * 16 + l16];
#pragma unroll
                for (int r = 0; r < 4; ++r) s[nt][r] = acc[nt][r] * mm + bb;
            }
            float mx[4];
#pragma unroll
            for (int r = 0; r < 4; ++r)
                mx[r] = fmaxf(fmaxf(s[0][r], s[1][r]), fmaxf(s[2][r], s[3][r]));
#pragma unroll
            for (int off = 1; off < 16; off <<= 1)
#pragma unroll
                for (int r = 0; r < 4; ++r) mx[r] = fmaxf(mx[r], __shfl_xor(mx[r], off));
            float al[4];
#pragma unroll
            for (int r = 0; r < 4; ++r) {
                float mn = fmaxf(m_run[rt][r], mx[r]);
                al[r] = __expf(m_run[rt][r] - mn);
                m_run[rt][r] = mn;
            }
            float ps[4] = {0.f, 0.f, 0.f, 0.f};
            int prow = wave * 32 + rt * 16;
#pragma unroll
            for (int nt = 0; nt < 4; ++nt)
#pragma unroll
                for (int r = 0; r < 4; ++r) {
                    float p = __expf(s[nt][r] - m_run[rt][r]);
                    ps[r] += p;
                    Psh[(prow + quad * 4 + r) * KP + nt * 16 + l16] = f2bf(p);
                }
#pragma unroll
            for (int off = 1; off < 16; off <<= 1)
#pragma unroll
                for (int r = 0; r < 4; ++r) ps[r] += __shfl_xor(ps[r], off);
#pragma unroll
            for (int r = 0; r < 4; ++r) l_run[rt][r] = l_run[rt][r] * al[r] + ps[r];
#pragma unroll
            for (int dn = 0; dn < 4; ++dn)
#pragma unroll
                for (int r = 0; r < 4; ++r) o[rt][dn][r] *= al[r];
#pragma unroll
            for (int dn = 0; dn < 4; ++dn)
#pragma unroll
                for (int ks = 0; ks < 2; ++ks) {
                    s16x8 af = ld_frag(&Psh[(prow + l16) * KP + ks * 32 + quad * 8]);
                    s16x8 bf = ld_frag(&Vsh[(dn * 16 + l16) * KP + ks * 32 + quad * 8]);
                    o[rt][dn] = MFMA16(af, bf, o[rt][dn]);
                }
        }
    }
    size_t pbase = ((size_t)bh * 8 + ck) * NL;
#pragma unroll
    for (int rt = 0; rt < 2; ++rt)
#pragma unroll
        for (int dn = 0; dn < 4; ++dn)
#pragma unroll
            for (int r = 0; r < 4; ++r) {
                int row = R0 + rt * 16 + quad * 4 + r;
                Opart[(pbase + row) * HD + dn * 16 + l16] = o[rt][dn][r];
            }
    if (l16 == 0) {
#pragma unroll
        for (int rt = 0; rt < 2; ++rt)
#pragma unroll
            for (int r = 0; r < 4; ++r) {
                int row = R0 + rt * 16 + quad * 4 + r;
                Mpart[pbase + row] = m_run[rt][r];
                Lpart[pbase + row] = l_run[rt][r];
            }
    }
}

// ---------------- 6b. combine key-split partials -> A ----------------
__global__ __launch_bounds__(256) void k3c_kernel(const float* __restrict__ Opart,
                                                  const float* __restrict__ Mpart,
                                                  const float* __restrict__ Lpart,
                                                  float* __restrict__ A) {
    int bh = blockIdx.y;
    int tid = threadIdx.x;
    int r = blockIdx.x * 64 + (tid >> 2);
    int dg = (tid & 3) * 16;
    size_t base = (size_t)bh * 8 * NL;
    float m[8], Mx = -1e30f;
#pragma unroll
    for (int ck = 0; ck < 8; ++ck) { m[ck] = Mpart[base + ck * NL + r]; Mx = fmaxf(Mx, m[ck]); }
    float w[8], l = 0.f;
#pragma unroll
    for (int ck = 0; ck < 8; ++ck) { w[ck] = __expf(m[ck] - Mx); l += w[ck] * Lpart[base + ck * NL + r]; }
    float inv = 1.f / l;
#pragma unroll
    for (int d4 = 0; d4 < 16; d4 += 4) {
        float4 acc = make_float4(0.f, 0.f, 0.f, 0.f);
#pragma unroll
        for (int ck = 0; ck < 8; ++ck) {
            float4 v = *(const float4*)&Opart[(base + ck * NL + r) * HD + dg + d4];
            acc.x += w[ck] * v.x; acc.y += w[ck] * v.y; acc.z += w[ck] * v.z; acc.w += w[ck] * v.w;
        }
        acc.x *= inv; acc.y *= inv; acc.z *= inv; acc.w *= inv;
        *(float4*)&A[((size_t)bh * NL + r) * HD + dg + d4] = acc;
    }
}

// ---------------- 7. W = Vinv @ A ----------------
__global__ __launch_bounds__(256) void w_kernel(const float* __restrict__ Vinv, const float* __restrict__ A,
                                                float* __restrict__ W) {
    int bh = blockIdx.y;
    int r0 = blockIdx.x * 32;
    __shared__ float Ash[128][64];
    __shared__ float Vl[32][129];
    int tid = threadIdx.x;
    for (int idx = tid; idx < 8192; idx += 256) Ash[idx >> 6][idx & 63] = A[(size_t)bh * 8192 + idx];
    for (int idx = tid; idx < 4096; idx += 256) {
        int r = idx >> 7, k = idx & 127;
        Vl[r][k] = Vinv[(size_t)bh * 16384 + (size_t)(r0 + r) * NL + k];
    }
    __syncthreads();
    int d = tid & 63, rg = tid >> 6;
    float acc[8] = {};
    for (int k = 0; k < NL; ++k) {
        float av = Ash[k][d];
#pragma unroll
        for (int i = 0; i < 8; ++i) acc[i] += Vl[rg * 8 + i][k] * av;
    }
#pragma unroll
    for (int i = 0; i < 8; ++i)
        W[(size_t)bh * 8192 + (size_t)(r0 + rg * 8 + i) * HD + d] = acc[i];
}

// ---------------- 8. X = softmax(Qs @ Klm^T) @ W, bf16 MFMA ----------------
// grid (64,48): block = 64 Q-rows, 4 waves x 16 rows.
#define QP 72
#define WP 136
__global__ __launch_bounds__(256) void k1x_mfma(const float* __restrict__ Q, const float* __restrict__ M,
                                                const float* __restrict__ Klm, const float* __restrict__ W,
                                                float* __restrict__ out) {
    int bh = blockIdx.y, b = bh / NH, q0 = blockIdx.x * 64;
    int tid = threadIdx.x;
    int wave = tid >> 6, lane = tid & 63, quad = lane >> 4, l16 = lane & 15;
    __shared__ ushort_t Qsh[64 * QP];
    __shared__ ushort_t Bsh[128 * QP];   // Klm tile; reused for P (64*WP=8704 <= 9216)
    __shared__ ushort_t Wt[64 * WP];     // W^T bf16 [d][lm]
    const float4* Qg = (const float4*)(Q + ((size_t)bh * SQ + q0) * HD);
#pragma unroll
    for (int rep = 0; rep < 4; ++rep) {
        int idx = rep * 256 + tid;       // 1024 float4 = 64 rows x 16
        int r = idx >> 4, d4 = (idx & 15) * 4;
        float4 x = Qg[idx];
        float mm = M[b * SQ + q0 + r] * SCALE;
        *(uint2*)&Qsh[r * QP + d4] = make_uint2(pack2(x.x * mm, x.y * mm), pack2(x.z * mm, x.w * mm));
    }
    const float4* Kg = (const float4*)(Klm + (size_t)bh * NL * HD);
#pragma unroll
    for (int rep = 0; rep < 8; ++rep) {
        int idx = rep * 256 + tid;       // 2048 float4 = 128 rows x 16
        int r = idx >> 4, d4 = (idx & 15) * 4;
        float4 x = Kg[idx];
        *(uint2*)&Bsh[r * QP + d4] = make_uint2(pack2(x.x, x.y), pack2(x.z, x.w));
    }
    const float4* Wg = (const float4*)(W + (size_t)bh * NL * HD);
#pragma unroll
    for (int rep = 0; rep < 8; ++rep) {
        int idx = rep * 256 + tid;       // 2048 float4 = 128 lm x 16
        int lm = idx >> 4, d4 = (idx & 15) * 4;
        float4 x = Wg[idx];
        Wt[(d4 + 0) * WP + lm] = f2bf(x.x);
        Wt[(d4 + 1) * WP + lm] = f2bf(x.y);
        Wt[(d4 + 2) * WP + lm] = f2bf(x.z);
        Wt[(d4 + 3) * WP + lm] = f2bf(x.w);
    }
    __syncthreads();
    int R = wave * 16;
    s16x8 aq[2];
#pragma unroll
    for (int ks = 0; ks < 2; ++ks) aq[ks] = ld_frag(&Qsh[(R + l16) * QP + ks * 32 + quad * 8]);
    f32x4 acc[8];
#pragma unroll
    for (int nt = 0; nt < 8; ++nt) acc[nt] = (f32x4){0.f, 0.f, 0.f, 0.f};
#pragma unroll
    for (int nt = 0; nt < 8; ++nt)
#pragma unroll
        for (int ks = 0; ks < 2; ++ks) {
            s16x8 bf = ld_frag(&Bsh[(nt * 16 + l16) * QP + ks * 32 + quad * 8]);
            acc[nt] = MFMA16(aq[ks], bf, acc[nt]);
        }
    float mx[4];
#pragma unroll
    for (int r = 0; r < 4; ++r) {
        mx[r] = acc[0][r];
#pragma unroll
        for (int nt = 1; nt < 8; ++nt) mx[r] = fmaxf(mx[r], acc[nt][r]);
    }
#pragma unroll
    for (int off = 1; off < 16; off <<= 1)
#pragma unroll
        for (int r = 0; r < 4; ++r) mx[r] = fmaxf(mx[r], __shfl_xor(mx[r], off));
    float ps[4] = {0.f, 0.f, 0.f, 0.f};
#pragma unroll
    for (int nt = 0; nt < 8; ++nt)
#pragma unroll
        for (int r = 0; r < 4; ++r) {
            float p = __expf(acc[nt][r] - mx[r]);
            acc[nt][r] = p;
            ps[r] += p;
        }
#pragma unroll
    for (int off = 1; off < 16; off <<= 1)
#pragma unroll
        for (int r = 0; r < 4; ++r) ps[r] += __shfl_xor(ps[r], off);
    float inv[4];
#pragma unroll
    for (int r = 0; r < 4; ++r) inv[r] = 1.f / ps[r];
    __syncthreads();                     // all waves done reading Bsh (Klm)
    ushort_t* Psh = Bsh;
#pragma unroll
    for (int nt = 0; nt < 8; ++nt)
#pragma unroll
        for (int r = 0; r < 4; ++r)
            Psh[(R + quad * 4 + r) * WP + nt * 16 + l16] = f2bf(acc[nt][r] * inv[r]);
    // PV: each wave reads only its own P rows -> no extra barrier (lgkmcnt orders within wave)
    f32x4 o[4];
#pragma unroll
    for (int dn = 0; dn < 4; ++dn) o[dn] = (f32x4){0.f, 0.f, 0.f, 0.f};
#pragma unroll
    for (int dn = 0; dn < 4; ++dn)
#pragma unroll
        for (int ks = 0; ks < 4; ++ks) {
            s16x8 af = ld_frag(&Psh[(R + l16) * WP + ks * 32 + quad * 8]);
            s16x8 bf = ld_frag(&Wt[(dn * 16 + l16) * WP + ks * 32 + quad * 8]);
            o[dn] = MFMA16(af, bf, o[dn]);
        }
    float* op = out + ((size_t)bh * SQ + q0) * HD;
#pragma unroll
    for (int dn = 0; dn < 4; ++dn)
#pragma unroll
        for (int r = 0; r < 4; ++r)
            op[(R + quad * 4 + r) * HD + dn * 16 + l16] = o[dn][r];
}

extern "C" void kernel_launch(void* const* d_in, const int* in_sizes, int n_in,
                              void* d_out, int out_size, void* d_ws, size_t ws_size,
                              hipStream_t stream) {
    const float* Q = (const float*)d_in[0];
    const float* K = (const float*)d_in[1];
    const float* V = (const float*)d_in[2];
    const float* M = (const float*)d_in[3];
    float* out = (float*)d_out;

    float* ws  = (float*)d_ws;
    float* Qlm = ws;                 // 48*128*64
    float* Klm = Qlm + 393216;
    float* K2  = Klm + 393216;       // 48*128*128
    float* Vm0 = K2  + 786432;
    float* Vm1 = Vm0 + 786432;
    float* KV  = Vm1 + 786432;
    float* T1  = KV  + 786432;
    float* T2  = T1  + 786432;
    float* Ab  = T2  + 786432;       // 48*128*64
    float* Wb  = Ab  + 393216;
    float* rowsum = Wb + 393216;     // 6144
    uint_t* scal  = (uint_t*)(rowsum + 6144);
    float* Mpart = rowsum + 6144 + 16;   // 48*8*128
    float* Lpart = Mpart + 49152;
    // Opart aliases Vm1..T2 (dead after Newton; 4*786432 = 3145728 = 48*8*128*64)
    float* Opart = Vm1;

    lm_kernel<<<dim3(6144, 2), 64, 0, stream>>>(Q, K, M, Qlm, Klm, scal);
    k2_kernel<<<6144, 128, 0, stream>>>(Qlm, Klm, K2, rowsum);
    colmax_kernel<<<48, 128, 0, stream>>>(K2, rowsum, scal);
    initv_kernel<<<6144, 128, 0, stream>>>(K2, scal, Vm0);

    float* Vc = Vm0; float* Vn = Vm1;
    for (int it = 0; it < 6; ++it) {
        nw_matmul<<<dim3(4, 48), 256, 0, stream>>>(K2, Vc, KV, 1.f, 0.f, 0);   // KV = Km@Vm
        nw_matmul<<<dim3(4, 48), 256, 0, stream>>>(KV, KV, T1, 1.f, 7.f, 1);   // T1 = KV@(7I-KV)
        nw_matmul<<<dim3(4, 48), 256, 0, stream>>>(KV, T1, T2, 1.f, 15.f, 1);  // T2 = KV@(15I-T1)
        nw_matmul<<<dim3(4, 48), 256, 0, stream>>>(Vc, T2, Vn, 0.25f, 13.f, 1);// Vn = .25*Vm@(13I-T2)
        float* t = Vc; Vc = Vn; Vn = t;
    }
    // after 6 iterations Vc == Vm0; Vm1/KV/T1/T2 are dead -> Opart may alias them

    k3v_mfma<<<dim3(8, 48), 256, 0, stream>>>(K, V, M, Qlm, Opart, Mpart, Lpart);
    k3c_kernel<<<dim3(2, 48), 256, 0, stream>>>(Opart, Mpart, Lpart, Ab);
    w_kernel<<<dim3(4, 48), 256, 0, stream>>>(Vc, Ab, Wb);
    k1x_mfma<<<dim3(64, 48), 256, 0, stream>>>(Q, M, Klm, Wb, out);
}